// Round 2
// baseline (598.778 us; speedup 1.0000x reference)
//
#include <hip/hip_runtime.h>
#include <stdint.h>

// Quant4-LUT matvec: y = x @ dequant(qweight, kmvalues)^T + bias
// HARNESS NOTE: integer inputs arrive as int32 — qweight is (28672, 4096)
// int32, each element holding ONE packed byte (lo nibble = even col, hi = odd).
// Total qweight traffic: 469.8 MB -> HBM-streaming kernel, roofline ~75 us.
//
// One wave per output row, 7 rows/wave (exact). Per-row 256-entry
// byte->half2 pair LUT in LDS (1 ds_read_b32 + 1 v_dot2_f32_f16 per code).
// Lane's x slice (128 values) packed once into 64 half2 VGPRs, reused
// across all 7 rows.

typedef _Float16 half2_t __attribute__((ext_vector_type(2)));

#define OUT_F     28672
#define ROW_ELEMS 4096                   // int32 code elements per row
#define NBLOCKS   1024
#define WPB       4                      // waves per block
#define NWAVES    (NBLOCKS * WPB)        // 4096
#define RPW       (OUT_F / NWAVES)       // 7 rows per wave, exact

__device__ __forceinline__ float dot2acc(half2_t a, half2_t b, float c) {
#if __has_builtin(__builtin_amdgcn_fdot2)
    return __builtin_amdgcn_fdot2(a, b, c, false);
#else
    return c + (float)a.x * (float)b.x + (float)a.y * (float)b.y;
#endif
}

__global__ __launch_bounds__(256) void q4lut_matvec(
    const float* __restrict__ x,
    const int*   __restrict__ qw,     // int32 per byte-code
    const float* __restrict__ kmv,
    const float* __restrict__ bias,
    float* __restrict__ out)
{
    __shared__ uint32_t pairlut[WPB][256];  // half2 bits: {lut[e&15], lut[e>>4]}

    const int tid   = threadIdx.x;
    const int wave  = tid >> 6;
    const int lane  = tid & 63;
    const int gwave = blockIdx.x * WPB + wave;

    // ---- Preload this lane's x slice.
    // Code element e = c*256 + lane*4 + k (c<16, k<4) covers x[2e], x[2e+1]
    // -> lane's x floats per chunk c: x[c*512 + lane*8 + 0..8).
    half2_t xp[64];
#pragma unroll
    for (int c = 0; c < 16; ++c) {
        const float4* xs = reinterpret_cast<const float4*>(x + c * 512 + lane * 8);
        float4 v0 = xs[0];
        float4 v1 = xs[1];
        xp[c * 4 + 0] = half2_t{(_Float16)v0.x, (_Float16)v0.y};
        xp[c * 4 + 1] = half2_t{(_Float16)v0.z, (_Float16)v0.w};
        xp[c * 4 + 2] = half2_t{(_Float16)v1.x, (_Float16)v1.y};
        xp[c * 4 + 3] = half2_t{(_Float16)v1.z, (_Float16)v1.w};
    }

    for (int r = 0; r < RPW; ++r) {
        const int row = gwave + NWAVES * r;

        // ---- Issue the whole row's code loads (16 KiB/wave, 1 KiB/instr).
        // Row = 4096 int32 = 1024 uint4; chunk c -> uint4 index c*64 + lane.
        const uint4* qrow =
            reinterpret_cast<const uint4*>(qw + (size_t)row * ROW_ELEMS);
        uint4 cs[16];
#pragma unroll
        for (int c = 0; c < 16; ++c) cs[c] = qrow[c * 64 + lane];

        // ---- Build the per-row byte->pair LUT via shuffles while loads fly.
        // Lane holds lut[lane & 15]; entry e = lane*4 + k needs
        // lo = lut[e & 15] = shfl(lane (lane&3)*4+k), hi = lut[e>>4] = shfl(lane>>2).
        const float    myv = kmv[row * 16 + (lane & 15)];
        const _Float16 hih = (_Float16)__shfl(myv, lane >> 2, 64);
        uint32_t ent[4];
#pragma unroll
        for (int k = 0; k < 4; ++k) {
            const _Float16 loh = (_Float16)__shfl(myv, ((lane & 3) << 2) + k, 64);
            half2_t p = {loh, hih};
            ent[k] = __builtin_bit_cast(uint32_t, p);
        }
        *reinterpret_cast<uint4*>(&pairlut[wave][lane * 4]) =
            make_uint4(ent[0], ent[1], ent[2], ent[3]);

        __syncthreads();  // LUT visible before lookups (also drains code loads)

        // ---- Hot loop: 1 ds_read_b32 + 1 fdot2 per code (2 weights).
        float acc = 0.f;
#pragma unroll
        for (int c = 0; c < 16; ++c) {
            const uint32_t dws[4] = {cs[c].x, cs[c].y, cs[c].z, cs[c].w};
#pragma unroll
            for (int k = 0; k < 4; ++k) {
                const uint32_t idx = dws[k] & 0xffu;   // int32 code, 0..255
                const uint32_t pw  = pairlut[wave][idx];
                acc = dot2acc(xp[c * 4 + k], __builtin_bit_cast(half2_t, pw), acc);
            }
        }

        // ---- Wave reduction + epilogue. (Next row's LUT overwrite is safe:
        // same-wave DS executes in order, and only this wave touches its slice.)
#pragma unroll
        for (int off = 32; off > 0; off >>= 1)
            acc += __shfl_xor(acc, off, 64);
        if (lane == 0) out[row] = acc + bias[row];
    }
}

extern "C" void kernel_launch(void* const* d_in, const int* in_sizes, int n_in,
                              void* d_out, int out_size, void* d_ws, size_t ws_size,
                              hipStream_t stream) {
    const float* x    = (const float*)d_in[0];
    const int*   qw   = (const int*)d_in[1];
    const float* kmv  = (const float*)d_in[2];
    const float* bias = (const float*)d_in[3];
    float*       out  = (float*)d_out;

    hipLaunchKernelGGL(q4lut_matvec, dim3(NBLOCKS), dim3(256), 0, stream,
                       x, qw, kmv, bias, out);
}